// Round 1
// 651.601 us; speedup vs baseline: 1.1306x; 1.1306x over previous
//
#include <hip/hip_runtime.h>
#include <hip/hip_bf16.h>
#include <math.h>

// Problem constants
#define B_N   4096
#define M_N   16
#define C_N   1000
#define K_TOP 4
#define EMB_N 100
#define XD    1000

// d_out layout (elements of the output dtype), reference return order:
// ems_out_post [4096*1000], child_loss [1], confidence_loss [1],
// ensemble_loss [1], wm_s [4096*16], true_confs [4096*16]
#define EMS_OFF 0
#define CH_OFF  4096000
#define CF_OFF  4096001
#define EN_OFF  4096002
#define WMS_OFF 4096003
#define TC_OFF  (4096003 + 65536)

__device__ __forceinline__ float bf2f(unsigned short u) {
    union { unsigned int i; float f; } v;
    v.i = ((unsigned int)u) << 16;
    return v.f;
}
__device__ __forceinline__ unsigned short f2bf(float f) {
    __hip_bfloat16 h = __float2bfloat16(f);
    union { __hip_bfloat16 h; unsigned short u; } v;
    v.h = h;
    return v.u;
}

// dtype-agnostic load/store helpers (F32=true: buffers are float32)
template<bool F32>
__device__ __forceinline__ float ldv(const void* p, size_t i) {
    if constexpr (F32) return ((const float*)p)[i];
    else return bf2f(((const unsigned short*)p)[i]);
}
template<bool F32>
__device__ __forceinline__ void ld4(const void* p, size_t i, float* o) {
    if constexpr (F32) {
        const float4 v = *reinterpret_cast<const float4*>((const float*)p + i);
        o[0] = v.x; o[1] = v.y; o[2] = v.z; o[3] = v.w;
    } else {
        const ushort4 u = *reinterpret_cast<const ushort4*>((const unsigned short*)p + i);
        o[0] = bf2f(u.x); o[1] = bf2f(u.y); o[2] = bf2f(u.z); o[3] = bf2f(u.w);
    }
}
template<bool F32>
__device__ __forceinline__ void stv(void* p, size_t i, float v) {
    if constexpr (F32) ((float*)p)[i] = v;
    else ((unsigned short*)p)[i] = f2bf(v);
}
template<bool F32>
__device__ __forceinline__ void st4(void* p, size_t i, const float* v) {
    if constexpr (F32) {
        float4 o; o.x = v[0]; o.y = v[1]; o.z = v[2]; o.w = v[3];
        *reinterpret_cast<float4*>((float*)p + i) = o;
    } else {
        ushort4 o; o.x = f2bf(v[0]); o.y = f2bf(v[1]); o.z = f2bf(v[2]); o.w = f2bf(v[3]);
        *reinterpret_cast<ushort4*>((unsigned short*)p + i) = o;
    }
}

// ---------------------------------------------------------------------------
// Probe: decide whether float buffers are f32 or bf16.
// If y_pred is bf16 N(0,1) data, even-indexed ushorts have exponent fields
// in ~[0x70,0x82]. If y_pred is f32, even-indexed ushorts are low mantissa
// bits -> exponent field ~uniform -> ~82% land outside [0x61,0x8F].
// Deterministic for fixed inputs -> graph-capture safe.
// ---------------------------------------------------------------------------
__global__ void probe_kernel(const unsigned short* __restrict__ y,
                             int* __restrict__ flag)
{
    const int t = threadIdx.x;
    unsigned short u = y[2 * t];          // even elements 0,2,...,126
    int e = (u >> 7) & 0xFF;
    bool weird = (e >= 0x90) || (e <= 0x60);
    unsigned long long m = __ballot(weird);
    if (t == 0) *flag = (__popcll(m) >= 16) ? 1 : 0;   // 1 => f32 buffers
}

// ---------------------------------------------------------------------------
// emb[m,e] = relu(model_emb[m,:] . w2_w[e,:] + w2_b[e])
// grid = 16 (one block per m), block = 128
// ---------------------------------------------------------------------------
template<bool F32>
__device__ __forceinline__ void emb_body(
    const void* __restrict__ model_emb,
    const void* __restrict__ w2_w,
    const void* __restrict__ w2_b,
    float* __restrict__ emb_out)
{
    const int m = blockIdx.x;
    const int tid = threadIdx.x;
    __shared__ float sx[XD];

    for (int k = tid; k < XD; k += 128)
        sx[k] = ldv<F32>(model_emb, (size_t)m * XD + k);
    __syncthreads();

    for (int e = tid; e < EMB_N; e += 128) {
        float s = 0.0f;
        #pragma unroll 4
        for (int k = 0; k < XD; k += 4) {
            float w[4];
            ld4<F32>(w2_w, (size_t)e * XD + k, w);
            s = fmaf(sx[k + 0], w[0], s);
            s = fmaf(sx[k + 1], w[1], s);
            s = fmaf(sx[k + 2], w[2], s);
            s = fmaf(sx[k + 3], w[3], s);
        }
        s += ldv<F32>(w2_b, e);
        emb_out[m * EMB_N + e] = fmaxf(s, 0.0f);
    }
}

__global__ __launch_bounds__(128) void emb_kernel(
    const void* model_emb, const void* w2_w, const void* w2_b,
    float* emb_out, const int* __restrict__ flag)
{
    if (*flag) emb_body<true>(model_emb, w2_w, w2_b, emb_out);
    else       emb_body<false>(model_emb, w2_w, w2_b, emb_out);
}

// ---------------------------------------------------------------------------
// routing: per b: feat = relu(x@W1^T+b1) [100], scores = feat@emb^T [16],
// weights = softplus(scores@W3^T + b3). grid = 4096, block = 128
// ---------------------------------------------------------------------------
template<bool F32>
__device__ __forceinline__ void routing_body(
    const void* __restrict__ x_in,
    const void* __restrict__ w1_w,
    const void* __restrict__ w1_b,
    const float* __restrict__ emb,
    const void* __restrict__ w3_w,
    const void* __restrict__ w3_b,
    float* __restrict__ weights_out)
{
    const int b = blockIdx.x;
    const int tid = threadIdx.x;
    __shared__ float sx[XD];
    __shared__ float sf[EMB_N];
    __shared__ float ss[M_N];

    for (int k = tid; k < XD; k += 128)
        sx[k] = ldv<F32>(x_in, (size_t)b * XD + k);
    __syncthreads();

    if (tid < EMB_N) {
        float s = 0.0f;
        #pragma unroll 4
        for (int k = 0; k < XD; k += 4) {
            float w[4];
            ld4<F32>(w1_w, (size_t)tid * XD + k, w);
            s = fmaf(sx[k + 0], w[0], s);
            s = fmaf(sx[k + 1], w[1], s);
            s = fmaf(sx[k + 2], w[2], s);
            s = fmaf(sx[k + 3], w[3], s);
        }
        s += ldv<F32>(w1_b, tid);
        sf[tid] = fmaxf(s, 0.0f);
    }
    __syncthreads();

    if (tid < M_N) {
        const float* er = emb + tid * EMB_N;
        float s = 0.0f;
        #pragma unroll
        for (int j = 0; j < EMB_N; j++) s = fmaf(sf[j], er[j], s);
        ss[tid] = s;
    }
    __syncthreads();

    if (tid < M_N) {
        float z = ldv<F32>(w3_b, tid);
        #pragma unroll
        for (int j = 0; j < M_N; j++)
            z = fmaf(ss[j], ldv<F32>(w3_w, tid * M_N + j), z);
        float sp = (z > 0.0f) ? (z + log1pf(__expf(-z))) : log1pf(__expf(z));
        weights_out[b * M_N + tid] = sp;
    }
}

__global__ __launch_bounds__(128) void routing_kernel(
    const void* x_in, const void* w1_w, const void* w1_b,
    const float* emb, const void* w3_w, const void* w3_b,
    float* weights_out, const int* __restrict__ flag)
{
    if (*flag) routing_body<true>(x_in, w1_w, w1_b, emb, w3_w, w3_b, weights_out);
    else       routing_body<false>(x_in, w1_w, w1_b, emb, w3_w, w3_b, weights_out);
}

// ---------------------------------------------------------------------------
// main fused kernel. grid = 4096 (block per b), block = 256.
// Thread t owns classes [4t, 4t+3] (250 active, exact cover of 1000).
// Per-block loss partials go to part[] (no contended atomics).
// ---------------------------------------------------------------------------
template<bool F32>
__device__ __forceinline__ void main_body(
    const void* __restrict__ y_pred,
    const int* __restrict__ labels,
    const float* __restrict__ weights,
    void* __restrict__ out,
    float* __restrict__ part)
{
    const int b = blockIdx.x;
    const int tid = threadIdx.x;
    const int lane = tid & 63;
    const int wave = tid >> 6;

    __shared__ float s_w[M_N], s_wmat[M_N], s_pw[M_N], s_wms[M_N];
    __shared__ float s_mask[M_N];
    __shared__ float s_den[M_N], s_lv[M_N], s_tcp[M_N], s_tc[M_N];
    __shared__ float s_red[4 * M_N];
    __shared__ float s_r4[4];
    __shared__ float s_acclab;

    const int label = labels[b];

    if (tid < M_N) s_w[tid] = weights[b * M_N + tid];
    __syncthreads();

    bool intop = false;
    float myw = 0.0f;
    if (tid < M_N) {
        myw = s_w[tid];
        float sum = 0.0f;
        #pragma unroll
        for (int j = 0; j < M_N; j++) sum += s_w[j];
        s_wmat[tid] = myw / fmaxf(sum, 1e-12f);
        int rank = 0;
        #pragma unroll
        for (int j = 0; j < M_N; j++) {
            float wj = s_w[j];
            rank += ((wj > myw) || (wj == myw && j < tid)) ? 1 : 0;
        }
        intop = (rank < K_TOP);
        s_mask[tid] = intop ? myw : 0.0f;
    }
    __syncthreads();
    if (tid < M_N) {
        float ts = 0.0f;
        #pragma unroll
        for (int j = 0; j < M_N; j++) ts += s_mask[j];
        s_pw[tid] = intop ? (myw / fmaxf(ts, 1e-12f)) : 0.0f;
        float es = 0.0f;
        #pragma unroll
        for (int j = 0; j < M_N; j++) es += __expf(s_wmat[j]);
        float wms = __expf(s_wmat[tid]) / es;
        s_wms[tid] = wms;
        stv<F32>(out, (size_t)WMS_OFF + b * M_N + tid, wms);
    }
    __syncthreads();

    float acc[4] = {0, 0, 0, 0}, accp[4] = {0, 0, 0, 0};
    float psum[M_N];
    const size_t ybase = (size_t)b * (M_N * C_N);
    const int c0 = tid * 4;
    const bool valid = (c0 < C_N);
    const int lrel = label - c0;

    #pragma unroll
    for (int m = 0; m < M_N; m++) {
        float vsum = 0.0f;
        if (valid) {
            float y[4];
            ld4<F32>(y_pred, ybase + m * C_N + c0, y);
            vsum = __expf(y[0]) + __expf(y[1]) + __expf(y[2]) + __expf(y[3]);
            float wm = s_wmat[m], pw = s_pw[m];
            acc[0] = fmaf(wm, y[0], acc[0]);
            acc[1] = fmaf(wm, y[1], acc[1]);
            acc[2] = fmaf(wm, y[2], acc[2]);
            acc[3] = fmaf(wm, y[3], acc[3]);
            accp[0] = fmaf(pw, y[0], accp[0]);
            accp[1] = fmaf(pw, y[1], accp[1]);
            accp[2] = fmaf(pw, y[2], accp[2]);
            accp[3] = fmaf(pw, y[3], accp[3]);
            if ((unsigned)lrel < 4u) s_lv[m] = y[lrel];
        }
        psum[m] = vsum;
    }

    #pragma unroll
    for (int m = 0; m < M_N; m++) {
        float v = psum[m];
        v += __shfl_down(v, 32);
        v += __shfl_down(v, 16);
        v += __shfl_down(v, 8);
        v += __shfl_down(v, 4);
        v += __shfl_down(v, 2);
        v += __shfl_down(v, 1);
        if (lane == 0) s_red[wave * M_N + m] = v;
    }

    float es_loc = 0.0f;
    if (valid) {
        es_loc = __expf(acc[0]) + __expf(acc[1]) + __expf(acc[2]) + __expf(acc[3]);
        if ((unsigned)lrel < 4u) s_acclab = acc[lrel];
        st4<F32>(out, (size_t)EMS_OFF + (size_t)b * C_N + c0, accp);
    }
    __syncthreads();

    if (tid < M_N) {
        s_den[tid] = s_red[tid] + s_red[M_N + tid] + s_red[2 * M_N + tid] + s_red[3 * M_N + tid];
    }
    {
        float v = es_loc;
        v += __shfl_down(v, 32);
        v += __shfl_down(v, 16);
        v += __shfl_down(v, 8);
        v += __shfl_down(v, 4);
        v += __shfl_down(v, 2);
        v += __shfl_down(v, 1);
        if (lane == 0) s_r4[wave] = v;
    }
    __syncthreads();

    if (tid < M_N) {
        s_tcp[tid] = __expf(s_lv[tid]) / s_den[tid];
    }
    __syncthreads();
    if (tid < M_N) {
        float ssum = 0.0f;
        #pragma unroll
        for (int j = 0; j < M_N; j++) ssum += __expf(s_tcp[j]);
        float tc = __expf(s_tcp[tid]) / ssum;
        s_tc[tid] = tc;
        stv<F32>(out, (size_t)TC_OFF + b * M_N + tid, tc);
    }
    __syncthreads();

    if (tid == 0) {
        float est = s_r4[0] + s_r4[1] + s_r4[2] + s_r4[3];
        float ens_part = logf(est) - s_acclab;
        float tsum = 0.0f;
        #pragma unroll
        for (int j = 0; j < M_N; j++) tsum += __expf(s_tc[j]);
        float child = 0.0f, conf = 0.0f;
        #pragma unroll
        for (int m = 0; m < M_N; m++) {
            float epl = logf(s_den[m]) - s_lv[m];
            child += epl * s_wms[m];
            float x = s_wms[m];
            float t = __expf(s_tc[m]) / tsum;
            conf += x - x * t + log1pf(__expf(-x));
        }
        // Per-block partials instead of contended same-address atomics.
        part[b]           = child;
        part[B_N + b]     = conf;
        part[2 * B_N + b] = ens_part;
    }
}

__global__ __launch_bounds__(256) void main_kernel(
    const void* y_pred, const int* labels, const float* weights,
    void* out, float* part, const int* __restrict__ flag)
{
    if (*flag) main_body<true>(y_pred, labels, weights, out, part);
    else       main_body<false>(y_pred, labels, weights, out, part);
}

// ---------------------------------------------------------------------------
// finalize: tree-reduce the 3 x 4096 per-block partials, write scalar losses.
// grid = 1, block = 256.
// ---------------------------------------------------------------------------
__global__ __launch_bounds__(256) void finalize_kernel(
    const float* __restrict__ part,
    void* __restrict__ out,
    const int* __restrict__ flag)
{
    const int tid = threadIdx.x;
    const int lane = tid & 63;
    const int wave = tid >> 6;
    __shared__ float sred[3][4];

    float s0 = 0.0f, s1 = 0.0f, s2 = 0.0f;
    for (int i = tid; i < B_N; i += 256) {
        s0 += part[i];
        s1 += part[B_N + i];
        s2 += part[2 * B_N + i];
    }
    #pragma unroll
    for (int off = 32; off >= 1; off >>= 1) {
        s0 += __shfl_down(s0, off);
        s1 += __shfl_down(s1, off);
        s2 += __shfl_down(s2, off);
    }
    if (lane == 0) { sred[0][wave] = s0; sred[1][wave] = s1; sred[2][wave] = s2; }
    __syncthreads();

    if (tid == 0) {
        const bool f32 = (*flag != 0);
        float child = sred[0][0] + sred[0][1] + sred[0][2] + sred[0][3];
        float conf  = sred[1][0] + sred[1][1] + sred[1][2] + sred[1][3];
        float ens   = sred[2][0] + sred[2][1] + sred[2][2] + sred[2][3];
        float vch = child / (float)(B_N * M_N);
        float vcf = conf  / (float)(B_N * M_N);
        float ven = ens   / (float)B_N;
        if (f32) {
            stv<true>(out, CH_OFF, vch);
            stv<true>(out, CF_OFF, vcf);
            stv<true>(out, EN_OFF, ven);
        } else {
            stv<false>(out, CH_OFF, vch);
            stv<false>(out, CF_OFF, vcf);
            stv<false>(out, EN_OFF, ven);
        }
    }
}

extern "C" void kernel_launch(void* const* d_in, const int* in_sizes, int n_in,
                              void* d_out, int out_size, void* d_ws, size_t ws_size,
                              hipStream_t stream)
{
    const void* x_in      = d_in[0];
    const void* y_pred    = d_in[1];
    const int*  labels    = (const int*)d_in[2];
    const void* model_emb = d_in[3];
    const void* w1_w      = d_in[4];
    const void* w1_b      = d_in[5];
    const void* w2_w      = d_in[6];
    const void* w2_b      = d_in[7];
    const void* w3_w      = d_in[8];
    const void* w3_b      = d_in[9];

    float* emb     = (float*)d_ws;           // 16*100 f32
    float* weights = emb + M_N * EMB_N;      // 4096*16 f32
    float* part    = weights + B_N * M_N;    // 3*4096 f32 per-block partials
    int*   flag    = (int*)(part + 3 * B_N); // dtype flag

    probe_kernel<<<1, 64, 0, stream>>>((const unsigned short*)y_pred, flag);
    emb_kernel<<<M_N, 128, 0, stream>>>(model_emb, w2_w, w2_b, emb, flag);
    routing_kernel<<<B_N, 128, 0, stream>>>(x_in, w1_w, w1_b, emb, w3_w, w3_b, weights, flag);
    main_kernel<<<B_N, 256, 0, stream>>>(y_pred, labels, weights, d_out, part, flag);
    finalize_kernel<<<1, 256, 0, stream>>>(part, d_out, flag);
}

// Round 3
// 493.210 us; speedup vs baseline: 1.4937x; 1.3211x over previous
//
#include <hip/hip_runtime.h>
#include <hip/hip_bf16.h>
#include <math.h>

// Problem constants
#define B_N   4096
#define M_N   16
#define C_N   1000
#define K_TOP 4
#define EMB_N 100
#define XD    1000

// d_out layout (elements of the output dtype), reference return order:
// ems_out_post [4096*1000], child_loss [1], confidence_loss [1],
// ensemble_loss [1], wm_s [4096*16], true_confs [4096*16]
#define EMS_OFF 0
#define CH_OFF  4096000
#define CF_OFF  4096001
#define EN_OFF  4096002
#define WMS_OFF 4096003
#define TC_OFF  (4096003 + 65536)

__device__ __forceinline__ float bf2f(unsigned short u) {
    union { unsigned int i; float f; } v;
    v.i = ((unsigned int)u) << 16;
    return v.f;
}
__device__ __forceinline__ unsigned short f2bf(float f) {
    __hip_bfloat16 h = __float2bfloat16(f);
    union { __hip_bfloat16 h; unsigned short u; } v;
    v.h = h;
    return v.u;
}

// dtype-agnostic load/store helpers (F32=true: buffers are float32)
template<bool F32>
__device__ __forceinline__ float ldv(const void* p, size_t i) {
    if constexpr (F32) return ((const float*)p)[i];
    else return bf2f(((const unsigned short*)p)[i]);
}
template<bool F32>
__device__ __forceinline__ void ld4(const void* p, size_t i, float* o) {
    if constexpr (F32) {
        const float4 v = *reinterpret_cast<const float4*>((const float*)p + i);
        o[0] = v.x; o[1] = v.y; o[2] = v.z; o[3] = v.w;
    } else {
        const ushort4 u = *reinterpret_cast<const ushort4*>((const unsigned short*)p + i);
        o[0] = bf2f(u.x); o[1] = bf2f(u.y); o[2] = bf2f(u.z); o[3] = bf2f(u.w);
    }
}
template<bool F32>
__device__ __forceinline__ void stv(void* p, size_t i, float v) {
    if constexpr (F32) ((float*)p)[i] = v;
    else ((unsigned short*)p)[i] = f2bf(v);
}
template<bool F32>
__device__ __forceinline__ void st4(void* p, size_t i, const float* v) {
    if constexpr (F32) {
        float4 o; o.x = v[0]; o.y = v[1]; o.z = v[2]; o.w = v[3];
        *reinterpret_cast<float4*>((float*)p + i) = o;
    } else {
        ushort4 o; o.x = f2bf(v[0]); o.y = f2bf(v[1]); o.z = f2bf(v[2]); o.w = f2bf(v[3]);
        *reinterpret_cast<ushort4*>((unsigned short*)p + i) = o;
    }
}

__device__ __forceinline__ float wave_sum(float v) {
    #pragma unroll
    for (int off = 32; off >= 1; off >>= 1) v += __shfl_xor(v, off);
    return v;
}

// ---------------------------------------------------------------------------
// Probe: decide whether float buffers are f32 or bf16.
// ---------------------------------------------------------------------------
__global__ void probe_kernel(const unsigned short* __restrict__ y,
                             int* __restrict__ flag)
{
    const int t = threadIdx.x;
    unsigned short u = y[2 * t];          // even elements 0,2,...,126
    int e = (u >> 7) & 0xFF;
    bool weird = (e >= 0x90) || (e <= 0x60);
    unsigned long long m = __ballot(weird);
    if (t == 0) *flag = (__popcll(m) >= 16) ? 1 : 0;   // 1 => f32 buffers
}

// ---------------------------------------------------------------------------
// emb[m,e] = relu(model_emb[m,:] . w2_w[e,:] + w2_b[e])
// v2: one block per output column e (grid=100, block=64 = 1 wave).
// Lanes sweep k (coalesced); w2 row staged in registers; 4 m-rows at a
// time for load MLP + independent reduce chains.
// ---------------------------------------------------------------------------
template<bool F32>
__device__ __forceinline__ void emb_body(
    const void* __restrict__ model_emb,
    const void* __restrict__ w2_w,
    const void* __restrict__ w2_b,
    float* __restrict__ emb_out)
{
    const int e = blockIdx.x;       // 0..99
    const int lane = threadIdx.x;   // 0..63

    float wr[4][4];
    #pragma unroll
    for (int p = 0; p < 4; p++) {
        const int k0 = lane * 4 + p * 256;
        if (k0 < XD) ld4<F32>(w2_w, (size_t)e * XD + k0, wr[p]);
        else { wr[p][0] = wr[p][1] = wr[p][2] = wr[p][3] = 0.0f; }
    }
    const float be = ldv<F32>(w2_b, e);

    for (int m0 = 0; m0 < M_N; m0 += 4) {
        float a0 = 0.f, a1 = 0.f, a2 = 0.f, a3 = 0.f;
        #pragma unroll
        for (int p = 0; p < 4; p++) {
            const int k0 = lane * 4 + p * 256;
            if (k0 < XD) {
                float m0v[4], m1v[4], m2v[4], m3v[4];
                ld4<F32>(model_emb, (size_t)(m0 + 0) * XD + k0, m0v);
                ld4<F32>(model_emb, (size_t)(m0 + 1) * XD + k0, m1v);
                ld4<F32>(model_emb, (size_t)(m0 + 2) * XD + k0, m2v);
                ld4<F32>(model_emb, (size_t)(m0 + 3) * XD + k0, m3v);
                #pragma unroll
                for (int j = 0; j < 4; j++) {
                    a0 = fmaf(wr[p][j], m0v[j], a0);
                    a1 = fmaf(wr[p][j], m1v[j], a1);
                    a2 = fmaf(wr[p][j], m2v[j], a2);
                    a3 = fmaf(wr[p][j], m3v[j], a3);
                }
            }
        }
        a0 = wave_sum(a0); a1 = wave_sum(a1);
        a2 = wave_sum(a2); a3 = wave_sum(a3);
        if (lane == 0) {
            emb_out[(m0 + 0) * EMB_N + e] = fmaxf(a0 + be, 0.0f);
            emb_out[(m0 + 1) * EMB_N + e] = fmaxf(a1 + be, 0.0f);
            emb_out[(m0 + 2) * EMB_N + e] = fmaxf(a2 + be, 0.0f);
            emb_out[(m0 + 3) * EMB_N + e] = fmaxf(a3 + be, 0.0f);
        }
    }
}

__global__ __launch_bounds__(64) void emb_kernel(
    const void* model_emb, const void* w2_w, const void* w2_b,
    float* emb_out, const int* __restrict__ flag)
{
    if (*flag) emb_body<true>(model_emb, w2_w, w2_b, emb_out);
    else       emb_body<false>(model_emb, w2_w, w2_b, emb_out);
}

// ---------------------------------------------------------------------------
// routing v2: one wave per batch row b. grid = 1024 blocks x 256 threads
// (4 waves -> 4 b's per block). Lanes sweep k (coalesced w1_w reads,
// killing the 8x L2 over-fetch of the per-thread-row layout). x row staged
// in 16 regs/lane. 4 e-rows concurrently (load MLP + reduce-chain ILP).
// Then per-wave epilogue: scores = feat@emb^T [16], softplus(W3@scores+b3).
// ---------------------------------------------------------------------------
template<bool F32>
__device__ __forceinline__ void routing_body(
    const void* __restrict__ x_in,
    const void* __restrict__ w1_w,
    const void* __restrict__ w1_b,
    const float* __restrict__ emb,
    const void* __restrict__ w3_w,
    const void* __restrict__ w3_b,
    float* __restrict__ weights_out)
{
    const int tid = threadIdx.x;
    const int wave = tid >> 6;
    const int lane = tid & 63;
    const int b = blockIdx.x * 4 + wave;

    __shared__ float sf[4][EMB_N];
    __shared__ float ss[4][M_N];

    // stage x row: k = lane*4 + p*256, 16 elements per lane
    float xr[4][4];
    #pragma unroll
    for (int p = 0; p < 4; p++) {
        const int k0 = lane * 4 + p * 256;
        if (k0 < XD) ld4<F32>(x_in, (size_t)b * XD + k0, xr[p]);
        else { xr[p][0] = xr[p][1] = xr[p][2] = xr[p][3] = 0.0f; }
    }

    for (int e0 = 0; e0 < EMB_N; e0 += 4) {
        float a0 = 0.f, a1 = 0.f, a2 = 0.f, a3 = 0.f;
        #pragma unroll
        for (int p = 0; p < 4; p++) {
            const int k0 = lane * 4 + p * 256;
            if (k0 < XD) {
                float w0[4], w1[4], w2[4], w3[4];
                ld4<F32>(w1_w, (size_t)(e0 + 0) * XD + k0, w0);
                ld4<F32>(w1_w, (size_t)(e0 + 1) * XD + k0, w1);
                ld4<F32>(w1_w, (size_t)(e0 + 2) * XD + k0, w2);
                ld4<F32>(w1_w, (size_t)(e0 + 3) * XD + k0, w3);
                #pragma unroll
                for (int j = 0; j < 4; j++) {
                    a0 = fmaf(xr[p][j], w0[j], a0);
                    a1 = fmaf(xr[p][j], w1[j], a1);
                    a2 = fmaf(xr[p][j], w2[j], a2);
                    a3 = fmaf(xr[p][j], w3[j], a3);
                }
            }
        }
        a0 = wave_sum(a0); a1 = wave_sum(a1);
        a2 = wave_sum(a2); a3 = wave_sum(a3);
        if (lane == 0) {
            sf[wave][e0 + 0] = fmaxf(a0 + ldv<F32>(w1_b, e0 + 0), 0.0f);
            sf[wave][e0 + 1] = fmaxf(a1 + ldv<F32>(w1_b, e0 + 1), 0.0f);
            sf[wave][e0 + 2] = fmaxf(a2 + ldv<F32>(w1_b, e0 + 2), 0.0f);
            sf[wave][e0 + 3] = fmaxf(a3 + ldv<F32>(w1_b, e0 + 3), 0.0f);
        }
    }
    __syncthreads();

    if (lane < M_N) {
        const float* er = emb + lane * EMB_N;
        float s = 0.0f;
        #pragma unroll 4
        for (int j = 0; j < EMB_N; j++) s = fmaf(sf[wave][j], er[j], s);
        ss[wave][lane] = s;
    }
    __syncthreads();

    if (lane < M_N) {
        float z = ldv<F32>(w3_b, lane);
        #pragma unroll
        for (int j = 0; j < M_N; j++)
            z = fmaf(ss[wave][j], ldv<F32>(w3_w, lane * M_N + j), z);
        float sp = (z > 0.0f) ? (z + log1pf(__expf(-z))) : log1pf(__expf(z));
        weights_out[b * M_N + lane] = sp;
    }
}

__global__ __launch_bounds__(256) void routing_kernel(
    const void* x_in, const void* w1_w, const void* w1_b,
    const float* emb, const void* w3_w, const void* w3_b,
    float* weights_out, const int* __restrict__ flag)
{
    if (*flag) routing_body<true>(x_in, w1_w, w1_b, emb, w3_w, w3_b, weights_out);
    else       routing_body<false>(x_in, w1_w, w1_b, emb, w3_w, w3_b, weights_out);
}

// ---------------------------------------------------------------------------
// main fused kernel. grid = 4096 (block per b), block = 256.
// Thread t owns classes [4t, 4t+3] (250 active, exact cover of 1000).
// m-loop processes 4 models per group with loads batched up-front (MLP=4;
// round-0 VGPR=32 showed serialized loads). Per-block loss partials to
// part[] (no contended atomics).
// ---------------------------------------------------------------------------
template<bool F32>
__device__ __forceinline__ void main_body(
    const void* __restrict__ y_pred,
    const int* __restrict__ labels,
    const float* __restrict__ weights,
    void* __restrict__ out,
    float* __restrict__ part)
{
    const int b = blockIdx.x;
    const int tid = threadIdx.x;
    const int lane = tid & 63;
    const int wave = tid >> 6;

    __shared__ float s_w[M_N], s_wmat[M_N], s_pw[M_N], s_wms[M_N];
    __shared__ float s_mask[M_N];
    __shared__ float s_den[M_N], s_lv[M_N], s_tcp[M_N], s_tc[M_N];
    __shared__ float s_red[4 * M_N];
    __shared__ float s_r4[4];
    __shared__ float s_acclab;

    const int label = labels[b];

    if (tid < M_N) s_w[tid] = weights[b * M_N + tid];
    __syncthreads();

    bool intop = false;
    float myw = 0.0f;
    if (tid < M_N) {
        myw = s_w[tid];
        float sum = 0.0f;
        #pragma unroll
        for (int j = 0; j < M_N; j++) sum += s_w[j];
        s_wmat[tid] = myw / fmaxf(sum, 1e-12f);
        int rank = 0;
        #pragma unroll
        for (int j = 0; j < M_N; j++) {
            float wj = s_w[j];
            rank += ((wj > myw) || (wj == myw && j < tid)) ? 1 : 0;
        }
        intop = (rank < K_TOP);
        s_mask[tid] = intop ? myw : 0.0f;
    }
    __syncthreads();
    if (tid < M_N) {
        float ts = 0.0f;
        #pragma unroll
        for (int j = 0; j < M_N; j++) ts += s_mask[j];
        s_pw[tid] = intop ? (myw / fmaxf(ts, 1e-12f)) : 0.0f;
        float es = 0.0f;
        #pragma unroll
        for (int j = 0; j < M_N; j++) es += __expf(s_wmat[j]);
        float wms = __expf(s_wmat[tid]) / es;
        s_wms[tid] = wms;
        stv<F32>(out, (size_t)WMS_OFF + b * M_N + tid, wms);
    }
    __syncthreads();

    float acc[4] = {0, 0, 0, 0}, accp[4] = {0, 0, 0, 0};
    float psum[M_N];
    const size_t ybase = (size_t)b * (M_N * C_N);
    const int c0 = tid * 4;
    const bool valid = (c0 < C_N);
    const int lrel = label - c0;

    #pragma unroll
    for (int m0 = 0; m0 < M_N; m0 += 4) {
        float y[4][4];
        if (valid) {
            // batched loads: 4 in flight before any use
            ld4<F32>(y_pred, ybase + (size_t)(m0 + 0) * C_N + c0, y[0]);
            ld4<F32>(y_pred, ybase + (size_t)(m0 + 1) * C_N + c0, y[1]);
            ld4<F32>(y_pred, ybase + (size_t)(m0 + 2) * C_N + c0, y[2]);
            ld4<F32>(y_pred, ybase + (size_t)(m0 + 3) * C_N + c0, y[3]);
        }
        #pragma unroll
        for (int i = 0; i < 4; i++) {
            const int m = m0 + i;
            float vsum = 0.0f;
            if (valid) {
                vsum = __expf(y[i][0]) + __expf(y[i][1]) + __expf(y[i][2]) + __expf(y[i][3]);
                float wm = s_wmat[m], pw = s_pw[m];
                acc[0] = fmaf(wm, y[i][0], acc[0]);
                acc[1] = fmaf(wm, y[i][1], acc[1]);
                acc[2] = fmaf(wm, y[i][2], acc[2]);
                acc[3] = fmaf(wm, y[i][3], acc[3]);
                accp[0] = fmaf(pw, y[i][0], accp[0]);
                accp[1] = fmaf(pw, y[i][1], accp[1]);
                accp[2] = fmaf(pw, y[i][2], accp[2]);
                accp[3] = fmaf(pw, y[i][3], accp[3]);
                if ((unsigned)lrel < 4u) s_lv[m] = y[i][lrel];
            }
            psum[m] = vsum;
        }
    }

    #pragma unroll
    for (int m = 0; m < M_N; m++) {
        float v = psum[m];
        v += __shfl_down(v, 32);
        v += __shfl_down(v, 16);
        v += __shfl_down(v, 8);
        v += __shfl_down(v, 4);
        v += __shfl_down(v, 2);
        v += __shfl_down(v, 1);
        if (lane == 0) s_red[wave * M_N + m] = v;
    }

    float es_loc = 0.0f;
    if (valid) {
        es_loc = __expf(acc[0]) + __expf(acc[1]) + __expf(acc[2]) + __expf(acc[3]);
        if ((unsigned)lrel < 4u) s_acclab = acc[lrel];
        st4<F32>(out, (size_t)EMS_OFF + (size_t)b * C_N + c0, accp);
    }
    __syncthreads();

    if (tid < M_N) {
        s_den[tid] = s_red[tid] + s_red[M_N + tid] + s_red[2 * M_N + tid] + s_red[3 * M_N + tid];
    }
    {
        float v = es_loc;
        v += __shfl_down(v, 32);
        v += __shfl_down(v, 16);
        v += __shfl_down(v, 8);
        v += __shfl_down(v, 4);
        v += __shfl_down(v, 2);
        v += __shfl_down(v, 1);
        if (lane == 0) s_r4[wave] = v;
    }
    __syncthreads();

    if (tid < M_N) {
        s_tcp[tid] = __expf(s_lv[tid]) / s_den[tid];
    }
    __syncthreads();
    if (tid < M_N) {
        float ssum = 0.0f;
        #pragma unroll
        for (int j = 0; j < M_N; j++) ssum += __expf(s_tcp[j]);
        float tc = __expf(s_tcp[tid]) / ssum;
        s_tc[tid] = tc;
        stv<F32>(out, (size_t)TC_OFF + b * M_N + tid, tc);
    }
    __syncthreads();

    if (tid == 0) {
        float est = s_r4[0] + s_r4[1] + s_r4[2] + s_r4[3];
        float ens_part = logf(est) - s_acclab;
        float tsum = 0.0f;
        #pragma unroll
        for (int j = 0; j < M_N; j++) tsum += __expf(s_tc[j]);
        float child = 0.0f, conf = 0.0f;
        #pragma unroll
        for (int m = 0; m < M_N; m++) {
            float epl = logf(s_den[m]) - s_lv[m];
            child += epl * s_wms[m];
            float x = s_wms[m];
            float t = __expf(s_tc[m]) / tsum;
            conf += x - x * t + log1pf(__expf(-x));
        }
        // Per-block partials instead of contended same-address atomics.
        part[b]           = child;
        part[B_N + b]     = conf;
        part[2 * B_N + b] = ens_part;
    }
}

__global__ __launch_bounds__(256) void main_kernel(
    const void* y_pred, const int* labels, const float* weights,
    void* out, float* part, const int* __restrict__ flag)
{
    if (*flag) main_body<true>(y_pred, labels, weights, out, part);
    else       main_body<false>(y_pred, labels, weights, out, part);
}

// ---------------------------------------------------------------------------
// finalize: tree-reduce the 3 x 4096 per-block partials, write scalar losses.
// ---------------------------------------------------------------------------
__global__ __launch_bounds__(256) void finalize_kernel(
    const float* __restrict__ part,
    void* __restrict__ out,
    const int* __restrict__ flag)
{
    const int tid = threadIdx.x;
    const int lane = tid & 63;
    const int wave = tid >> 6;
    __shared__ float sred[3][4];

    float s0 = 0.0f, s1 = 0.0f, s2 = 0.0f;
    for (int i = tid; i < B_N; i += 256) {
        s0 += part[i];
        s1 += part[B_N + i];
        s2 += part[2 * B_N + i];
    }
    #pragma unroll
    for (int off = 32; off >= 1; off >>= 1) {
        s0 += __shfl_down(s0, off);
        s1 += __shfl_down(s1, off);
        s2 += __shfl_down(s2, off);
    }
    if (lane == 0) { sred[0][wave] = s0; sred[1][wave] = s1; sred[2][wave] = s2; }
    __syncthreads();

    if (tid == 0) {
        const bool f32 = (*flag != 0);
        float child = sred[0][0] + sred[0][1] + sred[0][2] + sred[0][3];
        float conf  = sred[1][0] + sred[1][1] + sred[1][2] + sred[1][3];
        float ens   = sred[2][0] + sred[2][1] + sred[2][2] + sred[2][3];
        float vch = child / (float)(B_N * M_N);
        float vcf = conf  / (float)(B_N * M_N);
        float ven = ens   / (float)B_N;
        if (f32) {
            stv<true>(out, CH_OFF, vch);
            stv<true>(out, CF_OFF, vcf);
            stv<true>(out, EN_OFF, ven);
        } else {
            stv<false>(out, CH_OFF, vch);
            stv<false>(out, CF_OFF, vcf);
            stv<false>(out, EN_OFF, ven);
        }
    }
}

extern "C" void kernel_launch(void* const* d_in, const int* in_sizes, int n_in,
                              void* d_out, int out_size, void* d_ws, size_t ws_size,
                              hipStream_t stream)
{
    const void* x_in      = d_in[0];
    const void* y_pred    = d_in[1];
    const int*  labels    = (const int*)d_in[2];
    const void* model_emb = d_in[3];
    const void* w1_w      = d_in[4];
    const void* w1_b      = d_in[5];
    const void* w2_w      = d_in[6];
    const void* w2_b      = d_in[7];
    const void* w3_w      = d_in[8];
    const void* w3_b      = d_in[9];

    float* emb     = (float*)d_ws;           // 16*100 f32
    float* weights = emb + M_N * EMB_N;      // 4096*16 f32
    float* part    = weights + B_N * M_N;    // 3*4096 f32 per-block partials
    int*   flag    = (int*)(part + 3 * B_N); // dtype flag

    probe_kernel<<<1, 64, 0, stream>>>((const unsigned short*)y_pred, flag);
    emb_kernel<<<EMB_N, 64, 0, stream>>>(model_emb, w2_w, w2_b, emb, flag);
    routing_kernel<<<B_N / 4, 256, 0, stream>>>(x_in, w1_w, w1_b, emb, w3_w, w3_b, weights, flag);
    main_kernel<<<B_N, 256, 0, stream>>>(y_pred, labels, weights, d_out, part, flag);
    finalize_kernel<<<1, 256, 0, stream>>>(part, d_out, flag);
}